// Round 15
// baseline (238.206 us; speedup 1.0000x reference)
//
#include <hip/hip_runtime.h>
#include <hip/hip_bf16.h>

#define NN 10000
#define EE 320000
#define EALL (EE + NN)   // 330000 edges incl. self loops
#define BG 64
#define AOUT 1024
#define CAP 128          // slot capacity per node (deg ~ Poisson(32)+1; P(>=128) ~ 1e-40)

#define SCB ((EALL + 255) / 256)   // scatter blocks in fused dispatch (1290)

typedef __hip_bfloat16 bf16;
typedef __attribute__((ext_vector_type(8))) short bf16x8;
typedef __attribute__((ext_vector_type(4))) float f32x4;

__device__ __forceinline__ unsigned short f2bf(float f) {
    bf16 h = __float2bfloat16(f);
    return *reinterpret_cast<unsigned short*>(&h);
}
__device__ __forceinline__ float bf2f(unsigned short u) {
    bf16 h;
    *reinterpret_cast<unsigned short*>(&h) = u;
    return __bfloat162float(h);
}
// raw int read with uniform dtype branch (fi=1: int32, fi=0: int64)
__device__ __forceinline__ int iread(const void* p, int fi, long long idx) {
    return fi ? ((const int*)p)[idx] : (int)((const long long*)p)[idx];
}
// raw float read with uniform dtype branch (ff=1: fp32, ff=0: bf16)
__device__ __forceinline__ float fread1(const void* p, int ff, int idx) {
    return ff ? ((const float*)p)[idx] : bf2f(((const unsigned short*)p)[idx]);
}

// ====== R29 cvt: ONLY the 9 small attention/bias vectors (1728 f32) + W1/W2/W3 -> bf16^T
//        + cnt zeroing. Dead fp32 copies of W1/W2/W3 removed; k_final reads its weights RAW.
struct WPtrs { const void* p[20]; };
#define CVT_TOT (1728 + 32768 + 65536 + 16384 + NN)
__global__ __launch_bounds__(256) void k_cvt_all(WPtrs wp, const void* __restrict__ xsrc,
                          float* __restrict__ wfv,
                          unsigned short* __restrict__ w1t, unsigned short* __restrict__ w2t,
                          unsigned short* __restrict__ w3t, int* __restrict__ cnt, int ffh) {
    __shared__ int sff;
    int ff = ffh;
    if (ffh < 0) {   // sample leading 16K x-halves: any bf16-NaN pattern => fp32 storage
        const int t = threadIdx.x;
        bool nanp = false;
        const uint4* xs4 = (const uint4*)xsrc;
        uint4 a = xs4[t * 8 + 0], b = xs4[t * 8 + 4];
        const unsigned int wds[8] = {a.x, a.y, a.z, a.w, b.x, b.y, b.z, b.w};
#pragma unroll
        for (int k = 0; k < 8; k++) {
            unsigned int w2 = wds[k];
            if ((w2 & 0x7F80u) == 0x7F80u || ((w2 >> 16) & 0x7F80u) == 0x7F80u) nanp = true;
        }
        unsigned long long bn = __ballot(nanp);
        if (t == 0) sff = 0;
        __syncthreads();
        if ((t & 63) == 0 && bn) atomicOr(&sff, 1);
        __syncthreads();
        ff = sff;
    }

    int i = blockIdx.x * 256 + threadIdx.x;
    if (i < 1728) {   // as1,ad1,b1, as2,ad2,b2 (256 each), as3,ad3,b3 (64 each)
        const int vsz[9]  = {256,256,256,256,256,256,64,64,64};
        const int vwp[9]  = {1,2,3,5,6,7,9,10,11};
        const int voff[9] = {0,256,512,768,1024,1280,1536,1600,1664};
        int seg = 0, off = 0;
        while (i - off >= vsz[seg]) { off += vsz[seg]; seg++; }
        int k = i - off;
        wfv[voff[seg] + k] = fread1(wp.p[vwp[seg]], ff, k);
        return;
    }
    i -= 1728;
    if (i < 32768) {  // W1 [128x256] -> w1t [256][128] bf16
        int k = i >> 8, c = i & 255;
        float v = fread1(wp.p[0], ff, i);
        w1t[c * 128 + k] = f2bf(v);
        return;
    }
    i -= 32768;
    if (i < 65536) {  // W2 [256x256] -> w2t [256][256] bf16
        int k = i >> 8, c = i & 255;
        float v = fread1(wp.p[4], ff, i);
        w2t[c * 256 + k] = f2bf(v);
        return;
    }
    i -= 65536;
    if (i < 16384) {  // W3 [256x64] -> w3t [64][256] bf16
        int k = i >> 6, c = i & 63;
        float v = fread1(wp.p[8], ff, i);
        w3t[c * 256 + k] = f2bf(v);
        return;
    }
    i -= 16384;
    if (i < NN) cnt[i] = 0;   // zero per-node slot counters for the capacity scatter
}

// ===== fused: capacity-slot scatter (blocks 0..SCB-1, RAW edges, order-free)
//       + layer-1 GEMM (blocks SCB.., RAW x staged+converted inline) =====
__global__ __launch_bounds__(256) void k_fuse1(const void* __restrict__ eisrc,
                                               const void* __restrict__ xsrc,
                                               int ffh, int fih,
                                               int* __restrict__ cnt, int* __restrict__ ssrc,
                                               const unsigned short* __restrict__ WT16,
                                               const float* __restrict__ asf,
                                               const float* __restrict__ adf,
                                               unsigned short* __restrict__ C16,
                                               float* __restrict__ sb, float* __restrict__ db) {
    constexpr int LDW = 40;
    __shared__ alignas(16) char smem[10240];
    __shared__ int sff, sfi;
    const int t = threadIdx.x;
    int ff = ffh, fi = fih;
    if (ffh < 0 || fih < 0) {   // L2-broadcast sampling (all blocks reach identical decision)
        bool nanp = false, odd = false;
        const uint4* xs4 = (const uint4*)xsrc;
        uint4 a = xs4[t * 8 + 0], b = xs4[t * 8 + 4];
        const unsigned int wds[8] = {a.x, a.y, a.z, a.w, b.x, b.y, b.z, b.w};
#pragma unroll
        for (int k = 0; k < 8; k++) {
            unsigned int w2 = wds[k];
            if ((w2 & 0x7F80u) == 0x7F80u || ((w2 >> 16) & 0x7F80u) == 0x7F80u) nanp = true;
        }
        odd = ((const unsigned int*)eisrc)[2 * t + 1] != 0u;
        unsigned long long bn = __ballot(nanp);
        unsigned long long bo = __ballot(odd);
        if (t == 0) { sff = 0; sfi = 0; }
        __syncthreads();
        if ((t & 63) == 0) {
            if (bn) atomicOr(&sff, 1);
            if (bo) atomicOr(&sfi, 1);
        }
        __syncthreads();
        ff = (ffh >= 0) ? ffh : sff;
        fi = (fih >= 0) ? fih : sfi;
    }

    if (blockIdx.x < SCB) {
        // ---- edge-parallel capacity scatter: 1 global atomic per edge ----
        int e = blockIdx.x * 256 + t;
        if (e < EALL) {
            int dst = (e < EE) ? iread(eisrc, fi, (long long)EE + e) : (e - EE);
            int src = (e < EE) ? iread(eisrc, fi, e) : dst;
            int pos = atomicAdd(&cnt[dst], 1);
            if (pos < CAP) ssrc[(size_t)dst * CAP + pos] = src;   // guard: never OOB
        }
        return;
    }
    // ---- layer-1 GEMM (raw x, inline f2bf) ----
    unsigned short* As = (unsigned short*)smem;
    unsigned short* Bs = As + 64 * LDW;
    constexpr int K = 128, M = 256, H = M / 64;
    const int u = blockIdx.x - SCB;            // 0..627
    const int bx = u % 157;
    const int hh = u / 157;
    const int row0 = bx * 64, col0 = hh * 64;
    const int wv = t >> 6, lane = t & 63;
    const int m = lane & 15, q = lane >> 4;
    const int srow = t >> 2, skoff = (t & 3) * 8;

    f32x4 acc[4] = {};
    for (int k0 = 0; k0 < K; k0 += 32) {
        {
            int grow = row0 + srow;
            uint4 av = make_uint4(0u, 0u, 0u, 0u);
            if (grow < NN) {
                if (ff) {
                    const float* xp = (const float*)xsrc + (size_t)grow * K + k0 + skoff;
                    float4 fa = *(const float4*)xp;
                    float4 fb = *(const float4*)(xp + 4);
                    union { unsigned short u16[8]; uint4 v; } pk;
                    pk.u16[0] = f2bf(fa.x); pk.u16[1] = f2bf(fa.y);
                    pk.u16[2] = f2bf(fa.z); pk.u16[3] = f2bf(fa.w);
                    pk.u16[4] = f2bf(fb.x); pk.u16[5] = f2bf(fb.y);
                    pk.u16[6] = f2bf(fb.z); pk.u16[7] = f2bf(fb.w);
                    av = pk.v;
                } else {
                    av = *(const uint4*)((const unsigned short*)xsrc + (size_t)grow * K + k0 + skoff);
                }
            }
            *(uint4*)&As[srow * LDW + skoff] = av;
            uint4 bv = *(const uint4*)&WT16[(size_t)(col0 + srow) * K + k0 + skoff];
            *(uint4*)&Bs[srow * LDW + skoff] = bv;
        }
        __syncthreads();
        bf16x8 af = *(const bf16x8*)&As[(16 * wv + m) * LDW + q * 8];
#pragma unroll
        for (int ct = 0; ct < 4; ct++) {
            bf16x8 bfv = *(const bf16x8*)&Bs[(16 * ct + m) * LDW + q * 8];
            acc[ct] = __builtin_amdgcn_mfma_f32_16x16x32_bf16(af, bfv, acc[ct], 0, 0, 0);
        }
        __syncthreads();
    }
    float asv[4], adv[4];
#pragma unroll
    for (int ct = 0; ct < 4; ct++) {
        asv[ct] = asf[hh * 64 + 16 * ct + m];
        adv[ct] = adf[hh * 64 + 16 * ct + m];
    }
#pragma unroll
    for (int reg = 0; reg < 4; reg++) {
        int row = row0 + 16 * wv + q * 4 + reg;
        float ps = 0.f, pd = 0.f;
        if (row < NN) {
#pragma unroll
            for (int ct = 0; ct < 4; ct++) {
                float v = acc[ct][reg];
                C16[(size_t)row * M + col0 + 16 * ct + m] = f2bf(v);
                ps += v * asv[ct];
                pd += v * adv[ct];
            }
        }
#pragma unroll
        for (int off = 1; off < 16; off <<= 1) {
            ps += __shfl_xor(ps, off);
            pd += __shfl_xor(pd, off);
        }
        if (m == 0 && row < NN) { sb[row * H + hh] = ps; db[row * H + hh] = pd; }
    }
}

// ====== MFMA GEMM: h = A(bf16) @ W(bf16^T), 64x64/block, 16x16x32 mfma, fused s,d ======
template<int K, int M>
__global__ __launch_bounds__(256) void k_gemm(const unsigned short* __restrict__ A16,
                                              const unsigned short* __restrict__ WT16,
                                              const float* __restrict__ asf,
                                              const float* __restrict__ adf,
                                              unsigned short* __restrict__ C16,
                                              float* __restrict__ sb, float* __restrict__ db) {
    constexpr int BK = 32;
    constexpr int H = M / 64;
    constexpr int LDW = 40;
    __shared__ unsigned short As[64 * LDW];
    __shared__ unsigned short Bs[64 * LDW];
    const int row0 = blockIdx.x * 64;
    const int col0 = blockIdx.y * 64;
    const int hh = blockIdx.y;
    const int t = threadIdx.x;
    const int wv = t >> 6;
    const int lane = t & 63;
    const int m = lane & 15;
    const int q = lane >> 4;
    const int srow = t >> 2;
    const int skoff = (t & 3) * 8;

    f32x4 acc[4] = {};

    for (int k0 = 0; k0 < K; k0 += BK) {
        {
            int grow = row0 + srow;
            uint4 av = make_uint4(0u, 0u, 0u, 0u);
            if (grow < NN) av = *(const uint4*)&A16[(size_t)grow * K + k0 + skoff];
            *(uint4*)&As[srow * LDW + skoff] = av;
            uint4 bv = *(const uint4*)&WT16[(size_t)(col0 + srow) * K + k0 + skoff];
            *(uint4*)&Bs[srow * LDW + skoff] = bv;
        }
        __syncthreads();
        bf16x8 af = *(const bf16x8*)&As[(16 * wv + m) * LDW + q * 8];
#pragma unroll
        for (int ct = 0; ct < 4; ct++) {
            bf16x8 bfv = *(const bf16x8*)&Bs[(16 * ct + m) * LDW + q * 8];
            acc[ct] = __builtin_amdgcn_mfma_f32_16x16x32_bf16(af, bfv, acc[ct], 0, 0, 0);
        }
        __syncthreads();
    }

    float asv[4], adv[4];
#pragma unroll
    for (int ct = 0; ct < 4; ct++) {
        asv[ct] = asf[hh * 64 + 16 * ct + m];
        adv[ct] = adf[hh * 64 + 16 * ct + m];
    }
#pragma unroll
    for (int reg = 0; reg < 4; reg++) {
        int row = row0 + 16 * wv + q * 4 + reg;
        float ps = 0.f, pd = 0.f;
        if (row < NN) {
#pragma unroll
            for (int ct = 0; ct < 4; ct++) {
                float v = acc[ct][reg];
                C16[(size_t)row * M + col0 + 16 * ct + m] = f2bf(v);
                ps += v * asv[ct];
                pd += v * adv[ct];
            }
        }
#pragma unroll
        for (int off = 1; off < 16; off <<= 1) {
            ps += __shfl_xor(ps, off);
            pd += __shfl_xor(pd, off);
        }
        if (m == 0 && row < NN) { sb[row * H + hh] = ps; db[row * H + hh] = pd; }
    }
}

// ===== R29 agg4: 512 threads (16 edge subgroups x 32 channel groups) — halves the
// serial edge-loop latency chain vs eg=8. Barrier-free main loop (R12-proven pattern);
// per-thread acc order preserved; wsum is 8-term cross-wave sum (rounding only).
__global__ __launch_bounds__(512) void k_agg4(const unsigned short* __restrict__ hbuf16,
                                              const float* __restrict__ sb,
                                              const float* __restrict__ db,
                                              const int* __restrict__ cnt,
                                              const int* __restrict__ ssrc,
                                              const float* __restrict__ bias,
                                              unsigned short* __restrict__ out16) {
    const int n = blockIdx.x;
    const int tid = threadIdx.x;
    const int start = n * CAP;
    const int end = start + min(cnt[n], CAP);
    const int wv = tid >> 6, lane = tid & 63;
    const int cg = tid & 31;          // channel group 0..31 (8 channels each)
    const int eg = tid >> 5;          // edge subgroup 0..15
    const int chh = cg >> 3;          // head of this channel block
    __shared__ float accbuf[16 * 256];   // 16 KB
    __shared__ float sww[8][4];
    const float dn = db[n * 4 + chh];

    float wsum = 0.f;
    float acc[8] = {};
#pragma unroll 2
    for (int p = start + eg; p < end; p += 16) {
        int s = ssrc[p];                               // 32-lane broadcast load
        float e = sb[s * 4 + chh] + dn;
        e = e > 0.f ? e : 0.2f * e;
        float w2 = __expf(e);
        wsum += w2;
        const bf16x8 v = *(const bf16x8*)&hbuf16[(size_t)s * 256 + cg * 8];
#pragma unroll
        for (int i = 0; i < 8; i++)
            acc[i] += w2 * bf2f((unsigned short)v[i]);
    }
    {
        float* ab = &accbuf[eg * 256 + cg * 8];
#pragma unroll
        for (int i = 0; i < 8; i++) ab[i] = acc[i];
    }
    // wave wv holds egs {2wv, 2wv+1} at lane<32 / lane>=32 (same cg) -> pair via xor 32
    wsum += __shfl_xor(wsum, 32);
    if (lane < 32 && (cg & 7) == 0) sww[wv][chh] = wsum;   // lanes 0,8,16,24
    __syncthreads();

    if (tid < 256) {
        const int h2 = tid >> 6;
        float wsh = 0.f;
#pragma unroll
        for (int wq = 0; wq < 8; wq++) wsh += sww[wq][h2];
        float o = 0.f;
#pragma unroll
        for (int e8 = 0; e8 < 16; e8++) o += accbuf[e8 * 256 + tid];
        o = o / wsh + bias[tid];
        out16[(size_t)n * 256 + tid] = f2bf(fmaxf(o, 0.f));
    }
}

// ===== R29 agg1: wave-per-node, 4 nodes/block (body PROVEN correct in R13 mega) =====
__global__ __launch_bounds__(256) void k_agg1w(const unsigned short* __restrict__ hbuf16,
                                               const float* __restrict__ sb,
                                               const float* __restrict__ db,
                                               const int* __restrict__ cnt,
                                               const int* __restrict__ ssrc,
                                               const float* __restrict__ bias,
                                               unsigned short* __restrict__ out16) {
    __shared__ float accb[4 * 512];      // wave-private slices
    const int tid = threadIdx.x;
    const int wv = tid >> 6, lane = tid & 63;
    const int eg = lane >> 3, cg = lane & 7;
    const int n = blockIdx.x * 4 + wv;
    if (n >= NN) return;
    const int start = n * CAP;
    const int end = start + min(cnt[n], CAP);
    const float dn = db[n];
    float wsum = 0.f;
    float acc[8] = {};
#pragma unroll 4
    for (int p = start + eg; p < end; p += 8) {
        int s = ssrc[p];
        float e = sb[s] + dn;
        e = e > 0.f ? e : 0.2f * e;
        float w2 = __expf(e);
        wsum += w2;
        const bf16x8 v = *(const bf16x8*)&hbuf16[(size_t)s * 64 + cg * 8];
#pragma unroll
        for (int i = 0; i < 8; i++)
            acc[i] += w2 * bf2f((unsigned short)v[i]);
    }
    {
        float* ab = &accb[wv * 512 + eg * 64 + cg * 8];
#pragma unroll
        for (int i = 0; i < 8; i++) ab[i] = acc[i];
    }
    wsum += __shfl_xor(wsum, 8);
    wsum += __shfl_xor(wsum, 16);
    wsum += __shfl_xor(wsum, 32);
    // wave-internal LDS write->read: ordered by lgkmcnt within the wave; no barrier
    float o = 0.f;
#pragma unroll
    for (int e8 = 0; e8 < 8; e8++) o += accb[wv * 512 + e8 * 64 + lane];
    o = o / wsum + bias[lane];
    out16[(size_t)n * 64 + lane] = f2bf(fmaxf(o, 0.f));
}

// ====== fused: gstart binary search + pool -> hidden -> actor/critic out (RAW weights) =====
__global__ __launch_bounds__(256) void k_final(const unsigned short* __restrict__ feat16,
                                               const void* __restrict__ bsrc,
                                               const void* __restrict__ eisrc,
                                               const void* __restrict__ xsrc,
                                               int ffh, int fih,
                                               const void* __restrict__ Wa1, const void* __restrict__ ba1,
                                               const void* __restrict__ Wa2, const void* __restrict__ ba2,
                                               const void* __restrict__ Wc1, const void* __restrict__ bc1,
                                               const void* __restrict__ Wc2, const void* __restrict__ bc2,
                                               float* __restrict__ out) {
    __shared__ float red[256];
    __shared__ float p[64];
    __shared__ float a[64], cc[64];
    __shared__ int sff, sfi;
    const int g = blockIdx.x, t = threadIdx.x;
    int ff = ffh, fi = fih;
    if (ffh < 0 || fih < 0) {
        bool nanp = false, odd = false;
        const uint4* xs4 = (const uint4*)xsrc;
        uint4 av = xs4[t * 8 + 0], bv = xs4[t * 8 + 4];
        const unsigned int wds[8] = {av.x, av.y, av.z, av.w, bv.x, bv.y, bv.z, bv.w};
#pragma unroll
        for (int k = 0; k < 8; k++) {
            unsigned int w2 = wds[k];
            if ((w2 & 0x7F80u) == 0x7F80u || ((w2 >> 16) & 0x7F80u) == 0x7F80u) nanp = true;
        }
        odd = ((const unsigned int*)eisrc)[2 * t + 1] != 0u;
        unsigned long long bn = __ballot(nanp);
        unsigned long long bo = __ballot(odd);
        if (t == 0) { sff = 0; sfi = 0; }
        __syncthreads();
        if ((t & 63) == 0) {
            if (bn) atomicOr(&sff, 1);
            if (bo) atomicOr(&sfi, 1);
        }
        __syncthreads();
        ff = (ffh >= 0) ? ffh : sff;
        fi = (fih >= 0) ? fih : sfi;
    }
    // uniform binary searches: s = first n with batch[n] >= g; e = first with >= g+1
    int s, e;
    {
        int lo = 0, hi = NN;
        while (lo < hi) { int mid = (lo + hi) >> 1; if (iread(bsrc, fi, mid) < g) lo = mid + 1; else hi = mid; }
        s = lo;
        lo = 0; hi = NN;
        while (lo < hi) { int mid = (lo + hi) >> 1; if (iread(bsrc, fi, mid) < g + 1) lo = mid + 1; else hi = mid; }
        e = lo;
    }
    const int d = t & 63, c = t >> 6;
    float acc = 0.f;
    for (int n = s + c; n < e; n += 4) acc += bf2f(feat16[(size_t)n * 64 + d]);
    red[t] = acc; __syncthreads();
    if (c == 0) p[d] = (red[d] + red[64 + d] + red[128 + d] + red[192 + d])
                       / fmaxf((float)(e - s), 1.f);
    __syncthreads();
    if (t < 128) {
        int j = t & 63;
        const void* W  = (t < 64) ? Wa1 : Wc1;
        const void* bb = (t < 64) ? ba1 : bc1;
        float h = 0.f;
        if (ff) {
            const float* Wf = (const float*)W;
#pragma unroll 8
            for (int k = 0; k < 64; k++) h += p[k] * Wf[k * 64 + j];
        } else {
            const unsigned short* Wh = (const unsigned short*)W;
#pragma unroll 8
            for (int k = 0; k < 64; k++) h += p[k] * bf2f(Wh[k * 64 + j]);
        }
        h = fmaxf(h + fread1(bb, ff, j), 0.f);
        if (t < 64) a[j] = h; else cc[j] = h;
    }
    __syncthreads();
    float o[4] = {0.f, 0.f, 0.f, 0.f};
    if (ff) {
        const float* Wf = (const float*)Wa2;
        for (int k = 0; k < 64; k++) {
            float ak = a[k];
#pragma unroll
            for (int q = 0; q < 4; q++) o[q] += ak * Wf[k * AOUT + t + 256 * q];
        }
    } else {
        const unsigned short* Wh = (const unsigned short*)Wa2;
        for (int k = 0; k < 64; k++) {
            float ak = a[k];
#pragma unroll
            for (int q = 0; q < 4; q++) o[q] += ak * bf2f(Wh[k * AOUT + t + 256 * q]);
        }
    }
#pragma unroll
    for (int q = 0; q < 4; q++)
        out[g * AOUT + t + 256 * q] = tanhf(o[q] + fread1(ba2, ff, t + 256 * q));
    if (t == 0) {
        float v = 0.f;
        for (int k = 0; k < 64; k++) v += cc[k] * fread1(Wc2, ff, k);
        out[BG * AOUT + g] = v + fread1(bc2, ff, 0);
    }
}

extern "C" void kernel_launch(void* const* d_in, const int* in_sizes, int n_in,
                              void* d_out, int out_size, void* d_ws, size_t ws_size,
                              hipStream_t stream) {
    float* out = (float*)d_out;

    char* w = (char*)d_ws;
    auto alloc = [&](size_t bytes) { void* p = (void*)w; w += (bytes + 255) & ~size_t(255); return p; };
    float* wfv     = (float*)alloc((size_t)1728 * 4);
    unsigned short* w1t    = (unsigned short*)alloc((size_t)32768 * 2);
    unsigned short* w2t    = (unsigned short*)alloc((size_t)65536 * 2);
    unsigned short* w3t    = (unsigned short*)alloc((size_t)16384 * 2);
    unsigned short* actA16 = (unsigned short*)alloc((size_t)NN * 256 * 2);
    unsigned short* actB16 = (unsigned short*)alloc((size_t)NN * 256 * 2);
    float* sb      = (float*)alloc((size_t)NN * 4 * 4);
    float* db      = (float*)alloc((size_t)NN * 4 * 4);
    int*   cnt     = (int*)alloc((size_t)NN * 4);
    int*   ssrc    = (int*)alloc((size_t)NN * CAP * 4);

    // ---- host-side dtype decision from in_sizes (bytes); device samples otherwise ----
    int ffh = -1, fih = -1;
    if (in_sizes && n_in >= 2) {
        long long xs = in_sizes[0];
        if (xs == (long long)NN * 128 * 4) ffh = 1;
        else if (xs == (long long)NN * 128 * 2) ffh = 0;
        long long es = in_sizes[1];
        if (es == (long long)2 * EE * 8) fih = 0;
        else if (es == (long long)2 * EE * 4) fih = 1;
    }

    // ---- compact weight conversion + cnt zeroing ----
    WPtrs wp;
    for (int s = 0; s < 20; s++) wp.p[s] = d_in[3 + s];
    k_cvt_all<<<(CVT_TOT + 255) / 256, 256, 0, stream>>>(
        wp, d_in[0], wfv, w1t, w2t, w3t, cnt, ffh);

    const float *as1f = wfv + 0,   *ad1f = wfv + 256,  *b1f = wfv + 512;
    const float *as2f = wfv + 768, *ad2f = wfv + 1024, *b2f = wfv + 1280;
    const float *as3f = wfv + 1536,*ad3f = wfv + 1600, *b3f = wfv + 1664;

    // ---- fused: capacity-slot scatter (1290 blocks) + Layer-1 GEMM (628 blocks) ----
    k_fuse1<<<SCB + 628, 256, 0, stream>>>(d_in[1], d_in[0], ffh, fih, cnt, ssrc,
                                           w1t, as1f, ad1f, actA16, sb, db);

    // ---- Layer 1 aggregate (512-thread, 16 edge subgroups) ----
    k_agg4<<<NN, 512, 0, stream>>>(actA16, sb, db, cnt, ssrc, b1f, actB16);

    // ---- Layer 2 ----
    k_gemm<256, 256><<<dim3(157, 4), 256, 0, stream>>>(actB16, w2t, as2f, ad2f, actA16, sb, db);
    k_agg4<<<NN, 512, 0, stream>>>(actA16, sb, db, cnt, ssrc, b2f, actB16);

    // ---- Layer 3 ----
    k_gemm<256, 64><<<dim3(157, 1), 256, 0, stream>>>(actB16, w3t, as3f, ad3f, actA16, sb, db);
    k_agg1w<<<(NN + 3) / 4, 256, 0, stream>>>(actA16, sb, db, cnt, ssrc, b3f, actB16);

    // ---- fused gstart-search + pool + heads (raw weights) ----
    k_final<<<BG, 256, 0, stream>>>(actB16, d_in[2], d_in[1], d_in[0], ffh, fih,
                                    d_in[15], d_in[16], d_in[17], d_in[18],
                                    d_in[19], d_in[20], d_in[21], d_in[22], out);
}

// Round 16
// 225.058 us; speedup vs baseline: 1.0584x; 1.0584x over previous
//
#include <hip/hip_runtime.h>
#include <hip/hip_bf16.h>

#define NN 10000
#define EE 320000
#define EALL (EE + NN)   // 330000 edges incl. self loops
#define BG 64
#define AOUT 1024
#define CAP 128          // slot capacity per node (deg ~ Poisson(32)+1; P(>=128) ~ 1e-40)

#define SCB ((EALL + 255) / 256)   // scatter blocks in fused dispatch (1290)

typedef __hip_bfloat16 bf16;
typedef __attribute__((ext_vector_type(8))) short bf16x8;
typedef __attribute__((ext_vector_type(4))) float f32x4;

__device__ __forceinline__ unsigned short f2bf(float f) {
    bf16 h = __float2bfloat16(f);
    return *reinterpret_cast<unsigned short*>(&h);
}
__device__ __forceinline__ float bf2f(unsigned short u) {
    bf16 h;
    *reinterpret_cast<unsigned short*>(&h) = u;
    return __bfloat162float(h);
}
// raw int read with uniform dtype branch (fi=1: int32, fi=0: int64)
__device__ __forceinline__ int iread(const void* p, int fi, long long idx) {
    return fi ? ((const int*)p)[idx] : (int)((const long long*)p)[idx];
}
// raw float read with uniform dtype branch (ff=1: fp32, ff=0: bf16)
__device__ __forceinline__ float fread1(const void* p, int ff, int idx) {
    return ff ? ((const float*)p)[idx] : bf2f(((const unsigned short*)p)[idx]);
}

// ====== compact cvt: 9 small attention/bias vectors + W1/W2/W3 -> bf16^T + cnt zeroing ======
struct WPtrs { const void* p[20]; };
#define CVT_TOT (1728 + 32768 + 65536 + 16384 + NN)
__global__ __launch_bounds__(256) void k_cvt_all(WPtrs wp, const void* __restrict__ xsrc,
                          float* __restrict__ wfv,
                          unsigned short* __restrict__ w1t, unsigned short* __restrict__ w2t,
                          unsigned short* __restrict__ w3t, int* __restrict__ cnt, int ffh) {
    __shared__ int sff;
    int ff = ffh;
    if (ffh < 0) {   // sample leading 16K x-halves: any bf16-NaN pattern => fp32 storage
        const int t = threadIdx.x;
        bool nanp = false;
        const uint4* xs4 = (const uint4*)xsrc;
        uint4 a = xs4[t * 8 + 0], b = xs4[t * 8 + 4];
        const unsigned int wds[8] = {a.x, a.y, a.z, a.w, b.x, b.y, b.z, b.w};
#pragma unroll
        for (int k = 0; k < 8; k++) {
            unsigned int w2 = wds[k];
            if ((w2 & 0x7F80u) == 0x7F80u || ((w2 >> 16) & 0x7F80u) == 0x7F80u) nanp = true;
        }
        unsigned long long bn = __ballot(nanp);
        if (t == 0) sff = 0;
        __syncthreads();
        if ((t & 63) == 0 && bn) atomicOr(&sff, 1);
        __syncthreads();
        ff = sff;
    }

    int i = blockIdx.x * 256 + threadIdx.x;
    if (i < 1728) {   // as1,ad1,b1, as2,ad2,b2 (256 each), as3,ad3,b3 (64 each)
        const int vsz[9]  = {256,256,256,256,256,256,64,64,64};
        const int vwp[9]  = {1,2,3,5,6,7,9,10,11};
        const int voff[9] = {0,256,512,768,1024,1280,1536,1600,1664};
        int seg = 0, off = 0;
        while (i - off >= vsz[seg]) { off += vsz[seg]; seg++; }
        int k = i - off;
        wfv[voff[seg] + k] = fread1(wp.p[vwp[seg]], ff, k);
        return;
    }
    i -= 1728;
    if (i < 32768) {  // W1 [128x256] -> w1t [256][128] bf16
        int k = i >> 8, c = i & 255;
        float v = fread1(wp.p[0], ff, i);
        w1t[c * 128 + k] = f2bf(v);
        return;
    }
    i -= 32768;
    if (i < 65536) {  // W2 [256x256] -> w2t [256][256] bf16
        int k = i >> 8, c = i & 255;
        float v = fread1(wp.p[4], ff, i);
        w2t[c * 256 + k] = f2bf(v);
        return;
    }
    i -= 65536;
    if (i < 16384) {  // W3 [256x64] -> w3t [64][256] bf16
        int k = i >> 6, c = i & 63;
        float v = fread1(wp.p[8], ff, i);
        w3t[c * 256 + k] = f2bf(v);
        return;
    }
    i -= 16384;
    if (i < NN) cnt[i] = 0;   // zero per-node slot counters for the capacity scatter
}

// ===== fused: capacity-slot scatter (blocks 0..SCB-1, RAW edges, order-free)
//       + layer-1 GEMM (blocks SCB.., RAW x staged+converted inline) =====
__global__ __launch_bounds__(256) void k_fuse1(const void* __restrict__ eisrc,
                                               const void* __restrict__ xsrc,
                                               int ffh, int fih,
                                               int* __restrict__ cnt, int* __restrict__ ssrc,
                                               const unsigned short* __restrict__ WT16,
                                               const float* __restrict__ asf,
                                               const float* __restrict__ adf,
                                               unsigned short* __restrict__ C16,
                                               float* __restrict__ sb, float* __restrict__ db) {
    constexpr int LDW = 40;
    __shared__ alignas(16) char smem[10240];
    __shared__ int sff, sfi;
    const int t = threadIdx.x;
    int ff = ffh, fi = fih;
    if (ffh < 0 || fih < 0) {   // L2-broadcast sampling (all blocks reach identical decision)
        bool nanp = false, odd = false;
        const uint4* xs4 = (const uint4*)xsrc;
        uint4 a = xs4[t * 8 + 0], b = xs4[t * 8 + 4];
        const unsigned int wds[8] = {a.x, a.y, a.z, a.w, b.x, b.y, b.z, b.w};
#pragma unroll
        for (int k = 0; k < 8; k++) {
            unsigned int w2 = wds[k];
            if ((w2 & 0x7F80u) == 0x7F80u || ((w2 >> 16) & 0x7F80u) == 0x7F80u) nanp = true;
        }
        odd = ((const unsigned int*)eisrc)[2 * t + 1] != 0u;
        unsigned long long bn = __ballot(nanp);
        unsigned long long bo = __ballot(odd);
        if (t == 0) { sff = 0; sfi = 0; }
        __syncthreads();
        if ((t & 63) == 0) {
            if (bn) atomicOr(&sff, 1);
            if (bo) atomicOr(&sfi, 1);
        }
        __syncthreads();
        ff = (ffh >= 0) ? ffh : sff;
        fi = (fih >= 0) ? fih : sfi;
    }

    if (blockIdx.x < SCB) {
        // ---- edge-parallel capacity scatter: 1 global atomic per edge ----
        int e = blockIdx.x * 256 + t;
        if (e < EALL) {
            int dst = (e < EE) ? iread(eisrc, fi, (long long)EE + e) : (e - EE);
            int src = (e < EE) ? iread(eisrc, fi, e) : dst;
            int pos = atomicAdd(&cnt[dst], 1);
            if (pos < CAP) ssrc[(size_t)dst * CAP + pos] = src;   // guard: never OOB
        }
        return;
    }
    // ---- layer-1 GEMM (raw x, inline f2bf) ----
    unsigned short* As = (unsigned short*)smem;
    unsigned short* Bs = As + 64 * LDW;
    constexpr int K = 128, M = 256, H = M / 64;
    const int u = blockIdx.x - SCB;            // 0..627
    const int bx = u % 157;
    const int hh = u / 157;
    const int row0 = bx * 64, col0 = hh * 64;
    const int wv = t >> 6, lane = t & 63;
    const int m = lane & 15, q = lane >> 4;
    const int srow = t >> 2, skoff = (t & 3) * 8;

    f32x4 acc[4] = {};
    for (int k0 = 0; k0 < K; k0 += 32) {
        {
            int grow = row0 + srow;
            uint4 av = make_uint4(0u, 0u, 0u, 0u);
            if (grow < NN) {
                if (ff) {
                    const float* xp = (const float*)xsrc + (size_t)grow * K + k0 + skoff;
                    float4 fa = *(const float4*)xp;
                    float4 fb = *(const float4*)(xp + 4);
                    union { unsigned short u16[8]; uint4 v; } pk;
                    pk.u16[0] = f2bf(fa.x); pk.u16[1] = f2bf(fa.y);
                    pk.u16[2] = f2bf(fa.z); pk.u16[3] = f2bf(fa.w);
                    pk.u16[4] = f2bf(fb.x); pk.u16[5] = f2bf(fb.y);
                    pk.u16[6] = f2bf(fb.z); pk.u16[7] = f2bf(fb.w);
                    av = pk.v;
                } else {
                    av = *(const uint4*)((const unsigned short*)xsrc + (size_t)grow * K + k0 + skoff);
                }
            }
            *(uint4*)&As[srow * LDW + skoff] = av;
            uint4 bv = *(const uint4*)&WT16[(size_t)(col0 + srow) * K + k0 + skoff];
            *(uint4*)&Bs[srow * LDW + skoff] = bv;
        }
        __syncthreads();
        bf16x8 af = *(const bf16x8*)&As[(16 * wv + m) * LDW + q * 8];
#pragma unroll
        for (int ct = 0; ct < 4; ct++) {
            bf16x8 bfv = *(const bf16x8*)&Bs[(16 * ct + m) * LDW + q * 8];
            acc[ct] = __builtin_amdgcn_mfma_f32_16x16x32_bf16(af, bfv, acc[ct], 0, 0, 0);
        }
        __syncthreads();
    }
    float asv[4], adv[4];
#pragma unroll
    for (int ct = 0; ct < 4; ct++) {
        asv[ct] = asf[hh * 64 + 16 * ct + m];
        adv[ct] = adf[hh * 64 + 16 * ct + m];
    }
#pragma unroll
    for (int reg = 0; reg < 4; reg++) {
        int row = row0 + 16 * wv + q * 4 + reg;
        float ps = 0.f, pd = 0.f;
        if (row < NN) {
#pragma unroll
            for (int ct = 0; ct < 4; ct++) {
                float v = acc[ct][reg];
                C16[(size_t)row * M + col0 + 16 * ct + m] = f2bf(v);
                ps += v * asv[ct];
                pd += v * adv[ct];
            }
        }
#pragma unroll
        for (int off = 1; off < 16; off <<= 1) {
            ps += __shfl_xor(ps, off);
            pd += __shfl_xor(pd, off);
        }
        if (m == 0 && row < NN) { sb[row * H + hh] = ps; db[row * H + hh] = pd; }
    }
}

// ====== MFMA GEMM: h = A(bf16) @ W(bf16^T), 64x64/block, 16x16x32 mfma, fused s,d ======
template<int K, int M>
__global__ __launch_bounds__(256) void k_gemm(const unsigned short* __restrict__ A16,
                                              const unsigned short* __restrict__ WT16,
                                              const float* __restrict__ asf,
                                              const float* __restrict__ adf,
                                              unsigned short* __restrict__ C16,
                                              float* __restrict__ sb, float* __restrict__ db) {
    constexpr int BK = 32;
    constexpr int H = M / 64;
    constexpr int LDW = 40;
    __shared__ unsigned short As[64 * LDW];
    __shared__ unsigned short Bs[64 * LDW];
    const int row0 = blockIdx.x * 64;
    const int col0 = blockIdx.y * 64;
    const int hh = blockIdx.y;
    const int t = threadIdx.x;
    const int wv = t >> 6;
    const int lane = t & 63;
    const int m = lane & 15;
    const int q = lane >> 4;
    const int srow = t >> 2;
    const int skoff = (t & 3) * 8;

    f32x4 acc[4] = {};

    for (int k0 = 0; k0 < K; k0 += BK) {
        {
            int grow = row0 + srow;
            uint4 av = make_uint4(0u, 0u, 0u, 0u);
            if (grow < NN) av = *(const uint4*)&A16[(size_t)grow * K + k0 + skoff];
            *(uint4*)&As[srow * LDW + skoff] = av;
            uint4 bv = *(const uint4*)&WT16[(size_t)(col0 + srow) * K + k0 + skoff];
            *(uint4*)&Bs[srow * LDW + skoff] = bv;
        }
        __syncthreads();
        bf16x8 af = *(const bf16x8*)&As[(16 * wv + m) * LDW + q * 8];
#pragma unroll
        for (int ct = 0; ct < 4; ct++) {
            bf16x8 bfv = *(const bf16x8*)&Bs[(16 * ct + m) * LDW + q * 8];
            acc[ct] = __builtin_amdgcn_mfma_f32_16x16x32_bf16(af, bfv, acc[ct], 0, 0, 0);
        }
        __syncthreads();
    }

    float asv[4], adv[4];
#pragma unroll
    for (int ct = 0; ct < 4; ct++) {
        asv[ct] = asf[hh * 64 + 16 * ct + m];
        adv[ct] = adf[hh * 64 + 16 * ct + m];
    }
#pragma unroll
    for (int reg = 0; reg < 4; reg++) {
        int row = row0 + 16 * wv + q * 4 + reg;
        float ps = 0.f, pd = 0.f;
        if (row < NN) {
#pragma unroll
            for (int ct = 0; ct < 4; ct++) {
                float v = acc[ct][reg];
                C16[(size_t)row * M + col0 + 16 * ct + m] = f2bf(v);
                ps += v * asv[ct];
                pd += v * adv[ct];
            }
        }
#pragma unroll
        for (int off = 1; off < 16; off <<= 1) {
            ps += __shfl_xor(ps, off);
            pd += __shfl_xor(pd, off);
        }
        if (m == 0 && row < NN) { sb[row * H + hh] = ps; db[row * H + hh] = pd; }
    }
}

// ===== R14-proven agg: barrier-free main loop, eg=8, slot-bucket addressing =====
template<int H>
__global__ void k_agg(const unsigned short* __restrict__ hbuf16, const float* __restrict__ sb,
                      const float* __restrict__ db, const int* __restrict__ cnt,
                      const int* __restrict__ ssrc, const float* __restrict__ bias,
                      unsigned short* __restrict__ out16) {
    constexpr int M = H * 64;                  // 256 (H=4) or 64 (H=1); also blockDim.x
    constexpr int NW = M / 64;                 // waves per block
    constexpr int CG = M / 8;                  // 8-channel groups: 32 or 8
    constexpr int LCG = (H == 4) ? 5 : 3;
    const int n = blockIdx.x;
    const int tid = threadIdx.x;
    const int start = n * CAP;
    const int end = start + min(cnt[n], CAP);
    const int wv = tid >> 6;
    const int lane = tid & 63;
    const int cg = tid & (CG - 1);             // channel group
    const int eg = tid >> LCG;                 // edge subgroup 0..7
    const int chh = (H == 4) ? (cg >> 3) : 0;  // head of this thread's channel block
    __shared__ float accbuf[8 * M];            // [eg][channel]
    __shared__ float sww[NW][H];               // per-wave per-head wsum (H=4 only)
    const float dn = db[n * H + chh];

    // ---- single barrier-free sweep: inline weight + gather ----
    float wsum = 0.f;
    float acc[8] = {};
#pragma unroll 4
    for (int p = start + eg; p < end; p += 8) {
        int s = ssrc[p];                               // 32-lane broadcast load
        float e = sb[s * H + chh] + dn;
        e = e > 0.f ? e : 0.2f * e;
        float w2 = __expf(e);
        wsum += w2;
        const bf16x8 v = *(const bf16x8*)&hbuf16[(size_t)s * M + cg * 8];
#pragma unroll
        for (int i = 0; i < 8; i++)
            acc[i] += w2 * bf2f((unsigned short)v[i]);
    }

    // ---- dump per-thread acc to LDS; reduce wsum across eg ----
    {
        float* ab = &accbuf[eg * M + cg * 8];
#pragma unroll
        for (int i = 0; i < 8; i++) ab[i] = acc[i];
    }
    if constexpr (NW > 1) {
        wsum += __shfl_xor(wsum, 32);
        if (lane < 32 && (cg & 7) == 0) sww[wv][chh] = wsum;
    } else {
        wsum += __shfl_xor(wsum, 8);
        wsum += __shfl_xor(wsum, 16);
        wsum += __shfl_xor(wsum, 32);
    }
    __syncthreads();

    float wsh;
    if constexpr (NW > 1) {
        const int h2 = tid >> 6;
        wsh = sww[0][h2] + sww[1][h2] + sww[2][h2] + sww[3][h2];
    } else {
        wsh = wsum;
    }

    float o = 0.f;
#pragma unroll
    for (int e8 = 0; e8 < 8; e8++) o += accbuf[e8 * M + tid];
    o = o / wsh + bias[tid];
    out16[(size_t)n * M + tid] = f2bf(fmaxf(o, 0.f));
}

// ====== fused: gstart binary search + pool -> hidden -> actor/critic out (RAW weights) =====
__global__ __launch_bounds__(256) void k_final(const unsigned short* __restrict__ feat16,
                                               const void* __restrict__ bsrc,
                                               const void* __restrict__ eisrc,
                                               const void* __restrict__ xsrc,
                                               int ffh, int fih,
                                               const void* __restrict__ Wa1, const void* __restrict__ ba1,
                                               const void* __restrict__ Wa2, const void* __restrict__ ba2,
                                               const void* __restrict__ Wc1, const void* __restrict__ bc1,
                                               const void* __restrict__ Wc2, const void* __restrict__ bc2,
                                               float* __restrict__ out) {
    __shared__ float red[256];
    __shared__ float p[64];
    __shared__ float a[64], cc[64];
    __shared__ int sff, sfi;
    const int g = blockIdx.x, t = threadIdx.x;
    int ff = ffh, fi = fih;
    if (ffh < 0 || fih < 0) {
        bool nanp = false, odd = false;
        const uint4* xs4 = (const uint4*)xsrc;
        uint4 av = xs4[t * 8 + 0], bv = xs4[t * 8 + 4];
        const unsigned int wds[8] = {av.x, av.y, av.z, av.w, bv.x, bv.y, bv.z, bv.w};
#pragma unroll
        for (int k = 0; k < 8; k++) {
            unsigned int w2 = wds[k];
            if ((w2 & 0x7F80u) == 0x7F80u || ((w2 >> 16) & 0x7F80u) == 0x7F80u) nanp = true;
        }
        odd = ((const unsigned int*)eisrc)[2 * t + 1] != 0u;
        unsigned long long bn = __ballot(nanp);
        unsigned long long bo = __ballot(odd);
        if (t == 0) { sff = 0; sfi = 0; }
        __syncthreads();
        if ((t & 63) == 0) {
            if (bn) atomicOr(&sff, 1);
            if (bo) atomicOr(&sfi, 1);
        }
        __syncthreads();
        ff = (ffh >= 0) ? ffh : sff;
        fi = (fih >= 0) ? fih : sfi;
    }
    // uniform binary searches: s = first n with batch[n] >= g; e = first with >= g+1
    int s, e;
    {
        int lo = 0, hi = NN;
        while (lo < hi) { int mid = (lo + hi) >> 1; if (iread(bsrc, fi, mid) < g) lo = mid + 1; else hi = mid; }
        s = lo;
        lo = 0; hi = NN;
        while (lo < hi) { int mid = (lo + hi) >> 1; if (iread(bsrc, fi, mid) < g + 1) lo = mid + 1; else hi = mid; }
        e = lo;
    }
    const int d = t & 63, c = t >> 6;
    float acc = 0.f;
    for (int n = s + c; n < e; n += 4) acc += bf2f(feat16[(size_t)n * 64 + d]);
    red[t] = acc; __syncthreads();
    if (c == 0) p[d] = (red[d] + red[64 + d] + red[128 + d] + red[192 + d])
                       / fmaxf((float)(e - s), 1.f);
    __syncthreads();
    if (t < 128) {
        int j = t & 63;
        const void* W  = (t < 64) ? Wa1 : Wc1;
        const void* bb = (t < 64) ? ba1 : bc1;
        float h = 0.f;
        if (ff) {
            const float* Wf = (const float*)W;
#pragma unroll 8
            for (int k = 0; k < 64; k++) h += p[k] * Wf[k * 64 + j];
        } else {
            const unsigned short* Wh = (const unsigned short*)W;
#pragma unroll 8
            for (int k = 0; k < 64; k++) h += p[k] * bf2f(Wh[k * 64 + j]);
        }
        h = fmaxf(h + fread1(bb, ff, j), 0.f);
        if (t < 64) a[j] = h; else cc[j] = h;
    }
    __syncthreads();
    float o[4] = {0.f, 0.f, 0.f, 0.f};
    if (ff) {
        const float* Wf = (const float*)Wa2;
        for (int k = 0; k < 64; k++) {
            float ak = a[k];
#pragma unroll
            for (int q = 0; q < 4; q++) o[q] += ak * Wf[k * AOUT + t + 256 * q];
        }
    } else {
        const unsigned short* Wh = (const unsigned short*)Wa2;
        for (int k = 0; k < 64; k++) {
            float ak = a[k];
#pragma unroll
            for (int q = 0; q < 4; q++) o[q] += ak * bf2f(Wh[k * AOUT + t + 256 * q]);
        }
    }
#pragma unroll
    for (int q = 0; q < 4; q++)
        out[g * AOUT + t + 256 * q] = tanhf(o[q] + fread1(ba2, ff, t + 256 * q));
    if (t == 0) {
        float v = 0.f;
        for (int k = 0; k < 64; k++) v += cc[k] * fread1(Wc2, ff, k);
        out[BG * AOUT + g] = v + fread1(bc2, ff, 0);
    }
}

extern "C" void kernel_launch(void* const* d_in, const int* in_sizes, int n_in,
                              void* d_out, int out_size, void* d_ws, size_t ws_size,
                              hipStream_t stream) {
    float* out = (float*)d_out;

    char* w = (char*)d_ws;
    auto alloc = [&](size_t bytes) { void* p = (void*)w; w += (bytes + 255) & ~size_t(255); return p; };
    float* wfv     = (float*)alloc((size_t)1728 * 4);
    unsigned short* w1t    = (unsigned short*)alloc((size_t)32768 * 2);
    unsigned short* w2t    = (unsigned short*)alloc((size_t)65536 * 2);
    unsigned short* w3t    = (unsigned short*)alloc((size_t)16384 * 2);
    unsigned short* actA16 = (unsigned short*)alloc((size_t)NN * 256 * 2);
    unsigned short* actB16 = (unsigned short*)alloc((size_t)NN * 256 * 2);
    float* sb      = (float*)alloc((size_t)NN * 4 * 4);
    float* db      = (float*)alloc((size_t)NN * 4 * 4);
    int*   cnt     = (int*)alloc((size_t)NN * 4);
    int*   ssrc    = (int*)alloc((size_t)NN * CAP * 4);

    // ---- host-side dtype decision from in_sizes (bytes); device samples otherwise ----
    int ffh = -1, fih = -1;
    if (in_sizes && n_in >= 2) {
        long long xs = in_sizes[0];
        if (xs == (long long)NN * 128 * 4) ffh = 1;
        else if (xs == (long long)NN * 128 * 2) ffh = 0;
        long long es = in_sizes[1];
        if (es == (long long)2 * EE * 8) fih = 0;
        else if (es == (long long)2 * EE * 4) fih = 1;
    }

    // ---- compact weight conversion + cnt zeroing ----
    WPtrs wp;
    for (int s = 0; s < 20; s++) wp.p[s] = d_in[3 + s];
    k_cvt_all<<<(CVT_TOT + 255) / 256, 256, 0, stream>>>(
        wp, d_in[0], wfv, w1t, w2t, w3t, cnt, ffh);

    const float *as1f = wfv + 0,   *ad1f = wfv + 256,  *b1f = wfv + 512;
    const float *as2f = wfv + 768, *ad2f = wfv + 1024, *b2f = wfv + 1280;
    const float *as3f = wfv + 1536,*ad3f = wfv + 1600, *b3f = wfv + 1664;

    // ---- fused: capacity-slot scatter (1290 blocks) + Layer-1 GEMM (628 blocks) ----
    k_fuse1<<<SCB + 628, 256, 0, stream>>>(d_in[1], d_in[0], ffh, fih, cnt, ssrc,
                                           w1t, as1f, ad1f, actA16, sb, db);

    // ---- Layer 1 aggregate (R14-proven 256-thread, eg=8) ----
    k_agg<4><<<NN, 256, 0, stream>>>(actA16, sb, db, cnt, ssrc, b1f, actB16);

    // ---- Layer 2 ----
    k_gemm<256, 256><<<dim3(157, 4), 256, 0, stream>>>(actB16, w2t, as2f, ad2f, actA16, sb, db);
    k_agg<4><<<NN, 256, 0, stream>>>(actA16, sb, db, cnt, ssrc, b2f, actB16);

    // ---- Layer 3 ----
    k_gemm<256, 64><<<dim3(157, 1), 256, 0, stream>>>(actB16, w3t, as3f, ad3f, actA16, sb, db);
    k_agg<1><<<NN, 64, 0, stream>>>(actA16, sb, db, cnt, ssrc, b3f, actB16);

    // ---- fused gstart-search + pool + heads (raw weights) ----
    k_final<<<BG, 256, 0, stream>>>(actB16, d_in[2], d_in[1], d_in[0], ffh, fih,
                                    d_in[15], d_in[16], d_in[17], d_in[18],
                                    d_in[19], d_in[20], d_in[21], d_in[22], out);
}